// Round 4
// baseline (119588.098 us; speedup 1.0000x reference)
//
#include <hip/hip_runtime.h>
#include <hip/hip_bf16.h>

#define B_  256
#define T_  256
#define F_  64
#define U_  512
#define NG_ 2048   // 4*U
#define BU_ (B_ * U_)

typedef __attribute__((ext_vector_type(8))) short short8;
typedef __attribute__((ext_vector_type(16))) float floatx16;

__device__ __forceinline__ unsigned short f2bf(float f) {
    union { float f; unsigned int u; } v; v.f = f;
    unsigned int u = v.u;
    return (unsigned short)((u + 0x7FFFu + ((u >> 16) & 1u)) >> 16);
}
__device__ __forceinline__ float bf2f(unsigned short s) {
    union { unsigned int u; float f; } v; v.u = ((unsigned int)s) << 16;
    return v.f;
}

__global__ void cast_x_kernel(const float* __restrict__ x,
                              unsigned short* __restrict__ xb, int n) {
    int i = blockIdx.x * blockDim.x + threadIdx.x;
    if (i < n) xb[i] = f2bf(x[i]);
}

// Pack weights into 32x32x16 MFMA B-fragments, per unit-group (16 units -> 64
// block-local gate cols = 2 n32 tiles: [i16|f16] [g16|o16]).
__global__ void pack32_kernel(const float* __restrict__ W, const float* __restrict__ Uw,
                              unsigned short* __restrict__ dst, int KT, int KX) {
    long tid = (long)blockIdx.x * blockDim.x + threadIdx.x;
    long total = 32L * 2 * KT * 512;
    if (tid >= total) return;
    int j    = (int)(tid & 7);
    int lane = (int)((tid >> 3) & 63);
    int p512 = (int)(tid >> 9);
    int kt   = p512 % KT;
    int q    = p512 / KT;
    int nt   = q & 1;
    int ug   = q >> 1;
    int c    = nt * 32 + (lane & 31);
    int srcn = (c >> 4) * U_ + ug * 16 + (c & 15);
    int k    = kt * 16 + (lane >> 5) * 8 + j;
    float v  = (k < KX) ? W[(long)k * NG_ + srcn] : Uw[(long)(k - KX) * NG_ + srcn];
    dst[tid] = f2bf(v);
}

// ---- L2-tier (same-XCD) coherence primitives ----
// Producer: plain store (write-through L1 -> lands in this XCD's L2).
// Consumer: sc0 load (bypass L1, read this XCD's L2). All exchange partners
// are on ONE XCD (group = hardware XCC_ID), so L2 is the coherence point:
// every hop is an L2 hit (~200cy) instead of an LLC round trip (~600-900cy).
__device__ __forceinline__ short8 l2_load16(const unsigned short* p) {
    short8 r;
    asm volatile("global_load_dwordx4 %0, %1, off sc0" : "=v"(r) : "v"(p));
    return r;
}
__device__ __forceinline__ void st_u32(unsigned int* p, unsigned int v) {
    asm volatile("global_store_dword %0, %1, off" :: "v"(p), "v"(v) : "memory");
}
__device__ __forceinline__ void sys_store_u32(unsigned int* p, unsigned int v) {
    asm volatile("global_store_dword %0, %1, off sc0 sc1" :: "v"(p), "v"(v) : "memory");
}
#define VMWAIT(N) asm volatile("s_waitcnt vmcnt(" #N ")" ::: "memory")
__device__ __forceinline__ void dep8(short8& x) { asm volatile("" : "+v"(x)); }

#define MFMA32(a, b, c) __builtin_amdgcn_mfma_f32_32x32x16_bf16(a, b, c, 0, 0, 0)

// Poll a 32-word flag line (one word per producer block, all same XCD).
// 64 lanes read words (lane&31) with sc0; done when every word >= tgt.
__device__ __forceinline__ void wait_words(const int* line, int tgt) {
    const int* p = line + (threadIdx.x & 31);
    int guard = 0;
    for (;;) {
        int v;
        asm volatile("global_load_dword %0, %1, off sc0\n\ts_waitcnt vmcnt(0)"
                     : "=v"(v) : "v"(p) : "memory");
        if (__ballot(v >= tgt) == ~0ull) break;
        __builtin_amdgcn_s_sleep(1);
        if (++guard > (1 << 19)) break;   // fail visibly, never hang
    }
}

// Persistent 2-layer LSTM. 256 blocks x 256 thr = 1 block/CU (co-residency
// required and empirically guaranteed: prior rounds' spin protocol passed).
// Group formation: mo = REAL XCD id (s_getreg XCC_ID, m09-verified), ug =
// slot claimed via one startup atomicAdd -> robust to block->CU permutation;
// requires exactly 32 blocks/XCD (1/CU). If violated, guards trip -> visibly
// wrong answer, never a hang.
// iter k: phase A = L1 step k, phase B = L2 step k-1. Weights in VGPRs.
// Flags: per-(mo,ug) word; after L1 step k the word = k+1 (flags2: t2+1).
__global__ __launch_bounds__(256, 1) void lstm_persist(
    const unsigned short* __restrict__ xb,
    const unsigned short* __restrict__ P1,
    const unsigned short* __restrict__ P2,
    const float* __restrict__ b1, const float* __restrict__ b2,
    unsigned short* __restrict__ h1r, unsigned short* __restrict__ h2r,
    unsigned short* __restrict__ h2fin,
    int* flags1, int* flags2, int* xcdslots)
{
    const int tid  = threadIdx.x;
    const int w    = tid >> 6;       // wave 0..3 (k-split)
    const int lane = tid & 63;
    const int arow = lane & 31;
    const int koff = (lane >> 5) * 8;

    __shared__ int grp_s;
    if (tid == 0) {
        unsigned x;
        asm volatile("s_getreg_b32 %0, hwreg(HW_REG_XCC_ID)" : "=s"(x));
        x &= 7u;
        int slot = atomicAdd(xcdslots + x, 1) & 31;   // device-scope, one-time
        grp_s = (int)x | (slot << 3);
    }
    __shared__ float red[4][2][32][33];
    __shared__ float cst1[32][16];
    __shared__ float cst2[32][16];
    __shared__ float bias1_s[64], bias2_s[64];

    for (int i = tid; i < 512; i += 256) {
        cst1[i >> 4][i & 15] = 0.f;
        cst2[i >> 4][i & 15] = 0.f;
    }
    __syncthreads();
    const int mo  = grp_s & 7;       // REAL XCD id
    const int ug  = grp_s >> 3;      // slot within XCD: unit-group
    const int row = mo * 32 + arow;

    int* f1 = flags1 + mo * 32;      // one 128-B line per XCD, layer 1
    int* f2 = flags2 + mo * 32;

    if (tid < 64) {
        bias1_s[tid] = b1[(tid >> 4) * U_ + ug * 16 + (tid & 15)];
        bias2_s[tid] = b2[(tid >> 4) * U_ + ug * 16 + (tid & 15)];
    }

    // ---- load BOTH layers' B-fragments into registers (once) ----
    short8 a1f0[9], a1f1[9];     // L1: 36 ktiles of K=16, 9 per wave
    {
        const unsigned short* base = P1 + (size_t)ug * (2 * 36 * 512);
        #pragma unroll
        for (int i = 0; i < 9; ++i) {
            a1f0[i] = *(const short8*)(base + ((size_t)(0 * 36 + w * 9 + i) * 64 + lane) * 8);
            a1f1[i] = *(const short8*)(base + ((size_t)(1 * 36 + w * 9 + i) * 64 + lane) * 8);
        }
    }
    short8 b2f0[16], b2f1[16];   // L2: 64 ktiles; w0,w1 -> U2 half; w2,w3 -> W2 half
    {
        const unsigned short* base = P2 + (size_t)ug * (2 * 64 * 512);
        const int fb = (w < 2) ? (32 + w * 16) : ((w - 2) * 16);
        #pragma unroll
        for (int i = 0; i < 16; ++i) {
            b2f0[i] = *(const short8*)(base + ((size_t)(0 * 64 + fb + i) * 64 + lane) * 8);
            b2f1[i] = *(const short8*)(base + ((size_t)(1 * 64 + fb + i) * 64 + lane) * 8);
        }
    }
    __syncthreads();

    for (int k = 0; k <= T_; ++k) {
        const int t2 = k - 1;
        floatx16 accA0, accA1;
        #pragma unroll
        for (int i = 0; i < 16; ++i) { accA0[i] = 0.f; accA1[i] = 0.f; }

        // ---- pre-barrier: w0 computes x-part (flag-free), w3 polls f1
        if (w == 0) {
            if (k < T_) {
                const unsigned short* xbase = xb + ((size_t)row * T_ + k) * F_;
                #pragma unroll
                for (int i = 0; i < 4; ++i) {
                    short8 a = *(const short8*)(xbase + i * 16 + koff);
                    accA0 = MFMA32(a, a1f0[i], accA0);
                    accA1 = MFMA32(a, a1f1[i], accA1);
                }
            }
        } else if (w == 3) {
            if (k >= 1) wait_words(f1, k);   // all peers finished L1 step k-1
        }
        __syncthreads();
        __atomic_signal_fence(__ATOMIC_ACQUIRE);

        // ---- issue phase-A h1 loads + w2/3's phase-B h1 loads, batched ----
        short8 fA[9];
        const int nA = (k > 0 && k < T_) ? ((w == 0) ? 5 : 9) : 0;
        if (k > 0 && k < T_) {
            if (w == 0) {
                const unsigned short* hb = h1r + (size_t)((k - 1) & 3) * BU_
                                           + (size_t)row * U_;
                #pragma unroll
                for (int i = 0; i < 5; ++i) fA[i] = l2_load16(hb + i * 16 + koff);
            } else {
                const unsigned short* hb = h1r + (size_t)((k - 1) & 3) * BU_
                                           + (size_t)row * U_ + (w * 9 - 4) * 16;
                #pragma unroll
                for (int i = 0; i < 9; ++i) fA[i] = l2_load16(hb + i * 16 + koff);
            }
        }
        short8 fB[16];
        bool haveB = false;
        if (k >= 1 && w >= 2) {
            // W2 half: multiplies h1[t2] = h1[k-1], covered by the f1 wait above
            const unsigned short* hb = h1r + (size_t)(t2 & 3) * BU_
                                       + (size_t)row * U_ + ((w - 2) * 16) * 16;
            #pragma unroll
            for (int i = 0; i < 16; ++i) fB[i] = l2_load16(hb + i * 16 + koff);
            haveB = true;
        }

        // ================= phase A : layer-1 step t = k =================
        if (k < T_) {
            if (nA > 0) {
                if (haveB) { VMWAIT(16); } else { VMWAIT(0); }
                if (w == 0) {
                    #pragma unroll
                    for (int i = 0; i < 5; ++i) {
                        dep8(fA[i]);
                        accA0 = MFMA32(fA[i], a1f0[4 + i], accA0);
                        accA1 = MFMA32(fA[i], a1f1[4 + i], accA1);
                    }
                } else {
                    #pragma unroll
                    for (int i = 0; i < 9; ++i) {
                        dep8(fA[i]);
                        accA0 = MFMA32(fA[i], a1f0[i], accA0);
                        accA1 = MFMA32(fA[i], a1f1[i], accA1);
                    }
                }
            }

            // D layout: col=lane&31, row=(r&3)+8*(r>>2)+4*(lane>>5)
            #pragma unroll
            for (int r = 0; r < 16; ++r) {
                int rr = (r & 3) + 8 * (r >> 2) + 4 * (lane >> 5);
                red[w][0][rr][arow] = accA0[r];
                red[w][1][rr][arow] = accA1[r];
            }
            __syncthreads();

            {   // epilogue: 256 thr = 32 rows x 8 unit-pairs; one u32 plain store
                int u2 = (tid & 7) * 2;
                int r  = tid >> 3;
                unsigned int pk = 0;
                #pragma unroll
                for (int du = 0; du < 2; ++du) {
                    int u = u2 + du;
                    float zi = 0.f, zf = 0.f, zg = 0.f, zo = 0.f;
                    #pragma unroll
                    for (int ww = 0; ww < 4; ++ww) {
                        zi += red[ww][0][r][u];
                        zf += red[ww][0][r][16 + u];
                        zg += red[ww][1][r][u];
                        zo += red[ww][1][r][16 + u];
                    }
                    zi += bias1_s[u];      zf += bias1_s[16 + u];
                    zg += bias1_s[32 + u]; zo += bias1_s[48 + u];
                    float si = 1.f / (1.f + __expf(-zi));
                    float sf = 1.f / (1.f + __expf(-zf));
                    float so = 1.f / (1.f + __expf(-zo));
                    float gg = zg > 0.f ? zg : 0.f;
                    float cn = sf * cst1[r][u] + si * gg;
                    cst1[r][u] = cn;
                    float hn = so * (cn > 0.f ? cn : 0.f);
                    pk |= ((unsigned int)f2bf(hn)) << (16 * du);
                }
                unsigned int* hp = (unsigned int*)(h1r + (size_t)(k & 3) * BU_
                                   + (size_t)(mo * 32 + r) * U_ + ug * 16 + u2);
                st_u32(hp, pk);
            }
            __syncthreads();   // barrier drains vmcnt(0): h1 stores in L2
            __atomic_signal_fence(__ATOMIC_RELEASE);
            if (tid == 0) st_u32((unsigned int*)(f1 + ug), (unsigned int)(k + 1));
        }

        // ================= phase B : layer-2 step t2 = k-1 =================
        if (k >= 1) {
            floatx16 acc0, acc1;
            #pragma unroll
            for (int i = 0; i < 16; ++i) { acc0[i] = 0.f; acc1[i] = 0.f; }

            if (w < 2 && t2 > 0) {
                // U2 half: multiplies h2[t2-1]; deferred wait = phase-A of slack.
                wait_words(f2, t2);   // all peers finished L2 step t2-1
                __atomic_signal_fence(__ATOMIC_ACQUIRE);
                const unsigned short* hb = h2r + (size_t)((t2 - 1) & 3) * BU_
                                           + (size_t)row * U_ + (w * 16) * 16;
                #pragma unroll
                for (int i = 0; i < 16; ++i) fB[i] = l2_load16(hb + i * 16 + koff);
                haveB = true;
            }

            if (haveB) {
                VMWAIT(0);
                #pragma unroll
                for (int i = 0; i < 16; ++i) {
                    dep8(fB[i]);
                    acc0 = MFMA32(fB[i], b2f0[i], acc0);
                    acc1 = MFMA32(fB[i], b2f1[i], acc1);
                }
            }

            #pragma unroll
            for (int r = 0; r < 16; ++r) {
                int rr = (r & 3) + 8 * (r >> 2) + 4 * (lane >> 5);
                red[w][0][rr][arow] = acc0[r];
                red[w][1][rr][arow] = acc1[r];
            }
            __syncthreads();

            {
                int u2 = (tid & 7) * 2;
                int r  = tid >> 3;
                unsigned int pk = 0;
                #pragma unroll
                for (int du = 0; du < 2; ++du) {
                    int u = u2 + du;
                    float zi = 0.f, zf = 0.f, zg = 0.f, zo = 0.f;
                    #pragma unroll
                    for (int ww = 0; ww < 4; ++ww) {
                        zi += red[ww][0][r][u];
                        zf += red[ww][0][r][16 + u];
                        zg += red[ww][1][r][u];
                        zo += red[ww][1][r][16 + u];
                    }
                    zi += bias2_s[u];      zf += bias2_s[16 + u];
                    zg += bias2_s[32 + u]; zo += bias2_s[48 + u];
                    float si = 1.f / (1.f + __expf(-zi));
                    float sf = 1.f / (1.f + __expf(-zf));
                    float so = 1.f / (1.f + __expf(-zo));
                    float gg = zg > 0.f ? zg : 0.f;
                    float cn = sf * cst2[r][u] + si * gg;
                    cst2[r][u] = cn;
                    float hn = so * (cn > 0.f ? cn : 0.f);
                    pk |= ((unsigned int)f2bf(hn)) << (16 * du);
                }
                unsigned int* hp = (unsigned int*)(h2r + (size_t)(t2 & 3) * BU_
                                   + (size_t)(mo * 32 + r) * U_ + ug * 16 + u2);
                st_u32(hp, pk);
                if (t2 == T_ - 1) {
                    // final step: also publish system-scope for the dense kernel
                    unsigned int* fp = (unsigned int*)(h2fin
                                       + (size_t)(mo * 32 + r) * U_ + ug * 16 + u2);
                    sys_store_u32(fp, pk);
                }
            }
            __syncthreads();
            __atomic_signal_fence(__ATOMIC_RELEASE);
            if (tid == 0) st_u32((unsigned int*)(f2 + ug), (unsigned int)(t2 + 1));
        }
    }
}

__global__ void dense_kernel(const unsigned short* __restrict__ h2,
                             const float* __restrict__ Wd,
                             const float* __restrict__ bd,
                             float* __restrict__ out) {
    int b = blockIdx.x;
    int lane = threadIdx.x;                  // 64 lanes
    const unsigned short* hp = h2 + (long)b * U_ + lane * 8;
    float sum = 0.f;
    #pragma unroll
    for (int j = 0; j < 8; ++j) sum += bf2f(hp[j]) * Wd[lane * 8 + j];
    #pragma unroll
    for (int off = 32; off; off >>= 1) sum += __shfl_down(sum, off);
    if (lane == 0) out[b] = 1.f / (1.f + __expf(-(sum + bd[0])));
}

extern "C" void kernel_launch(void* const* d_in, const int* in_sizes, int n_in,
                              void* d_out, int out_size, void* d_ws, size_t ws_size,
                              hipStream_t stream) {
    const float* x  = (const float*)d_in[0];
    const float* W1 = (const float*)d_in[1];
    const float* U1 = (const float*)d_in[2];
    const float* b1 = (const float*)d_in[3];
    const float* W2 = (const float*)d_in[4];
    const float* U2 = (const float*)d_in[5];
    const float* b2 = (const float*)d_in[6];
    const float* Wd = (const float*)d_in[7];
    const float* bd = (const float*)d_in[8];
    float* out = (float*)d_out;

    char* ws = (char*)d_ws;
    size_t off = 0;
    unsigned short* xb    = (unsigned short*)(ws + off); off += (size_t)B_ * T_ * F_ * 2;      // 8.39 MB
    unsigned short* P1    = (unsigned short*)(ws + off); off += (size_t)32 * 2 * 36 * 512 * 2; // 2.36 MB
    unsigned short* P2    = (unsigned short*)(ws + off); off += (size_t)32 * 2 * 64 * 512 * 2; // 4.19 MB
    unsigned short* h1r   = (unsigned short*)(ws + off); off += (size_t)4 * BU_ * 2;           // 1 MB
    unsigned short* h2r   = (unsigned short*)(ws + off); off += (size_t)4 * BU_ * 2;           // 1 MB
    unsigned short* h2fin = (unsigned short*)(ws + off); off += (size_t)BU_ * 2;               // 256 KB
    int* flags1   = (int*)(ws + off); off += (size_t)8 * 32 * 4;     // 1 KB (one line/XCD)
    int* flags2   = (int*)(ws + off); off += (size_t)8 * 32 * 4;     // 1 KB
    int* xcdslots = (int*)(ws + off); off += (size_t)64 * 4;         // 256 B

    hipMemsetAsync(flags1, 0, (size_t)(8 * 32 * 4) * 2 + 64 * 4, stream);

    int n = B_ * T_ * F_;
    cast_x_kernel<<<(n + 255) / 256, 256, 0, stream>>>(x, xb, n);
    {
        long tot1 = 32L * 2 * 36 * 512;
        pack32_kernel<<<(int)((tot1 + 255) / 256), 256, 0, stream>>>(W1, U1, P1, 36, 64);
        long tot2 = 32L * 2 * 64 * 512;
        pack32_kernel<<<(int)((tot2 + 255) / 256), 256, 0, stream>>>(W2, U2, P2, 64, 512);
    }

    // 256 blocks = 1 block/CU: co-residency guaranteed, plain launch.
    lstm_persist<<<256, 256, 0, stream>>>(xb, P1, P2, b1, b2, h1r, h2r, h2fin,
                                          flags1, flags2, xcdslots);

    dense_kernel<<<B_, 64, 0, stream>>>(h2fin, Wd, bd, out);
}

// Round 6
// 2037.998 us; speedup vs baseline: 58.6792x; 58.6792x over previous
//
#include <hip/hip_runtime.h>
#include <hip/hip_bf16.h>

#define B_  256
#define T_  256
#define F_  64
#define U_  512
#define NG_ 2048   // 4*U
#define BU_ (B_ * U_)

typedef __attribute__((ext_vector_type(8))) short short8;
typedef __attribute__((ext_vector_type(16))) float floatx16;

__device__ __forceinline__ unsigned short f2bf(float f) {
    union { float f; unsigned int u; } v; v.f = f;
    unsigned int u = v.u;
    return (unsigned short)((u + 0x7FFFu + ((u >> 16) & 1u)) >> 16);
}
__device__ __forceinline__ float bf2f(unsigned short s) {
    union { unsigned int u; float f; } v; v.u = ((unsigned int)s) << 16;
    return v.f;
}

__global__ void cast_x_kernel(const float* __restrict__ x,
                              unsigned short* __restrict__ xb, int n) {
    int i = blockIdx.x * blockDim.x + threadIdx.x;
    if (i < n) xb[i] = f2bf(x[i]);
}

// Pack weights into 32x32x16 MFMA B-fragments, per unit-group (16 units -> 64
// block-local gate cols = 2 n32 tiles: [i16|f16] [g16|o16]).
__global__ void pack32_kernel(const float* __restrict__ W, const float* __restrict__ Uw,
                              unsigned short* __restrict__ dst, int KT, int KX) {
    long tid = (long)blockIdx.x * blockDim.x + threadIdx.x;
    long total = 32L * 2 * KT * 512;
    if (tid >= total) return;
    int j    = (int)(tid & 7);
    int lane = (int)((tid >> 3) & 63);
    int p512 = (int)(tid >> 9);
    int kt   = p512 % KT;
    int q    = p512 / KT;
    int nt   = q & 1;
    int ug   = q >> 1;
    int c    = nt * 32 + (lane & 31);
    int srcn = (c >> 4) * U_ + ug * 16 + (c & 15);
    int k    = kt * 16 + (lane >> 5) * 8 + j;
    float v  = (k < KX) ? W[(long)k * NG_ + srcn] : Uw[(long)(k - KX) * NG_ + srcn];
    dst[tid] = f2bf(v);
}

// System-scope (LLC coherence point) ops — the only semantics empirically
// proven coherent across blocks on this chip (r0-r2 passed; L2-tier r4 broke).
__device__ __forceinline__ short8 llc_load(const unsigned short* p) {
    short8 r;
    asm volatile("global_load_dwordx4 %0, %1, off sc0 sc1" : "=v"(r) : "v"(p));
    return r;
}
__device__ __forceinline__ void sys_store_u32(unsigned int* p, unsigned int v) {
    asm volatile("global_store_dword %0, %1, off sc0 sc1" :: "v"(p), "v"(v) : "memory");
}
#define VMWAIT(N) asm volatile("s_waitcnt vmcnt(" #N ")" ::: "memory")
__device__ __forceinline__ void dep8(short8& x) { asm volatile("" : "+v"(x)); }

#define MFMA32(a, b, c) __builtin_amdgcn_mfma_f32_32x32x16_bf16(a, b, c, 0, 0, 0)

// Batched re-issuable load of N 16-B fragments (compile-time N -> registers).
template<int N, int M>
__device__ __forceinline__ void load_llc(short8 (&d)[M], const unsigned short* b, int koff) {
    #pragma unroll
    for (int i = 0; i < N; ++i) d[i] = llc_load(b + i * 16 + koff);
}

// Retry until fresh. Every u32 word is either a fully-written h-pair
// (halfwords < 0x8000 since h >= 0) or the 0xFFFFFFFF poison.
// Ordering (rule #18): after VMWAIT, re-pin every fragment via volatile dep8
// BEFORE the check — the check then reads post-wait defs; plain C code cannot
// be hoisted above the wait because its operands are redefined after it.
template<int N, int M>
__device__ __forceinline__ void wait_fresh(short8 (&d)[M], const unsigned short* b, int koff) {
    int g = 0;
    for (;;) {
        VMWAIT(0);
        __builtin_amdgcn_sched_barrier(0);
        #pragma unroll
        for (int i = 0; i < N; ++i) dep8(d[i]);   // post-wait defs
        bool bad = false;
        #pragma unroll
        for (int i = 0; i < N; ++i) {
            union { short8 s; unsigned int w[4]; } u; u.s = d[i];
            #pragma unroll
            for (int j = 0; j < 4; ++j) bad |= (u.w[j] == 0xFFFFFFFFu);
        }
        if (__ballot(bad) == 0ull) break;
        if (++g > (1 << 15)) break;   // fail visibly, never hang
        load_llc<N>(d, b, koff);
    }
}

// Prologue: poison steps 0 and 1 of both h histories with system-scope stores
// (no host memset -> no dirty poison lines in any XCD L2 that could evict
// late and clobber fresh LLC data). Steps >= 2 are self-poisoned in-kernel.
__global__ void poison01_kernel(unsigned short* h1h, unsigned short* h2h) {
    int i = blockIdx.x * blockDim.x + threadIdx.x;   // over 2 steps * BU_/2 words
    if (i < 2 * (BU_ / 2)) {
        sys_store_u32((unsigned int*)h1h + i, 0xFFFFFFFFu);
        sys_store_u32((unsigned int*)h2h + i, 0xFFFFFFFFu);
    }
}

// Persistent 2-layer LSTM. 256 blocks x 256 thr = 1 block/CU.
// iter k: phase A = L1 step k, phase B = L2 step k-1. Weights in VGPRs.
// NO FLAGS: each timestep owns a write-once buffer; the sys-store of the data
// IS the signal. Consumers batch-load, wait, pin, check for poison, re-issue.
// Self-poison: at iter k each block poisons its OWN (mo,ug) slice of step k+2
// (ordered before its real write by program order + barrier drains; visible
// to consumers before their first read of step k+2 via the h1 dependence
// chain). Phase B validates fB for ALL waves (r5 bug: w2/3 at k=T raced).
__global__ __launch_bounds__(256, 1) void lstm_persist(
    const unsigned short* __restrict__ xb,
    const unsigned short* __restrict__ P1,
    const unsigned short* __restrict__ P2,
    const float* __restrict__ b1, const float* __restrict__ b2,
    unsigned short* __restrict__ h1h, unsigned short* __restrict__ h2h)
{
    const int bid  = blockIdx.x;     // 0..255
    const int mo   = bid & 7;        // m-octile (row-slab group)
    const int ug   = bid >> 3;       // 32 unit-groups of 16 units
    const int tid  = threadIdx.x;
    const int w    = tid >> 6;       // wave 0..3 (k-split)
    const int lane = tid & 63;
    const int arow = lane & 31;
    const int koff = (lane >> 5) * 8;
    const int row  = mo * 32 + arow;

    __shared__ float red[4][2][32][33];
    __shared__ float cst1[32][16];
    __shared__ float cst2[32][16];
    __shared__ float bias1_s[64], bias2_s[64];

    for (int i = tid; i < 512; i += 256) {
        cst1[i >> 4][i & 15] = 0.f;
        cst2[i >> 4][i & 15] = 0.f;
    }
    if (tid < 64) {
        bias1_s[tid] = b1[(tid >> 4) * U_ + ug * 16 + (tid & 15)];
        bias2_s[tid] = b2[(tid >> 4) * U_ + ug * 16 + (tid & 15)];
    }

    // ---- load BOTH layers' B-fragments into registers (once) ----
    short8 a1f0[9], a1f1[9];     // L1: 36 ktiles of K=16, 9 per wave
    {
        const unsigned short* base = P1 + (size_t)ug * (2 * 36 * 512);
        #pragma unroll
        for (int i = 0; i < 9; ++i) {
            a1f0[i] = *(const short8*)(base + ((size_t)(0 * 36 + w * 9 + i) * 64 + lane) * 8);
            a1f1[i] = *(const short8*)(base + ((size_t)(1 * 36 + w * 9 + i) * 64 + lane) * 8);
        }
    }
    short8 b2f0[16], b2f1[16];   // L2: 64 ktiles; w0,w1 -> U2 half; w2,w3 -> W2 half
    {
        const unsigned short* base = P2 + (size_t)ug * (2 * 64 * 512);
        const int fb = (w < 2) ? (32 + w * 16) : ((w - 2) * 16);
        #pragma unroll
        for (int i = 0; i < 16; ++i) {
            b2f0[i] = *(const short8*)(base + ((size_t)(0 * 64 + fb + i) * 64 + lane) * 8);
            b2f1[i] = *(const short8*)(base + ((size_t)(1 * 64 + fb + i) * 64 + lane) * 8);
        }
    }
    __syncthreads();

    for (int k = 0; k <= T_; ++k) {
        const int t2 = k - 1;
        floatx16 accA0, accA1;
        #pragma unroll
        for (int i = 0; i < 16; ++i) { accA0[i] = 0.f; accA1[i] = 0.f; }

        // ---- w0: x-part MFMAs (no cross-block dep) ----
        if (w == 0 && k < T_) {
            const unsigned short* xbase = xb + ((size_t)row * T_ + k) * F_;
            #pragma unroll
            for (int i = 0; i < 4; ++i) {
                short8 a = *(const short8*)(xbase + i * 16 + koff);
                accA0 = MFMA32(a, a1f0[i], accA0);
                accA1 = MFMA32(a, a1f1[i], accA1);
            }
        }

        // ---- self-poison step k+2 (own slice), fire-and-forget ----
        if (k + 2 < T_) {
            int u2 = (tid & 7) * 2, r = tid >> 3;
            size_t o = (size_t)(mo * 32 + r) * U_ + ug * 16 + u2;
            sys_store_u32((unsigned int*)(h1h + (size_t)(k + 2) * BU_ + o), 0xFFFFFFFFu);
            sys_store_u32((unsigned int*)(h2h + (size_t)(k + 2) * BU_ + o), 0xFFFFFFFFu);
        }

        // ---- issue ALL of this iteration's h loads, batched ----
        short8 fA[9];
        const unsigned short* hbA = nullptr;
        const int nA = (k > 0 && k < T_) ? ((w == 0) ? 5 : 9) : 0;
        if (nA) {
            hbA = h1h + (size_t)(k - 1) * BU_ + (size_t)row * U_
                  + ((w == 0) ? 0 : (w * 9 - 4) * 16);
            if (w == 0) load_llc<5>(fA, hbA, koff);
            else        load_llc<9>(fA, hbA, koff);
        }
        short8 fB[16];
        const unsigned short* hbB = nullptr;
        bool haveB = false;
        if (k >= 1 && w >= 2) {
            // W2 half: h1[t2] = h1[k-1] — same vintage as fA.
            hbB = h1h + (size_t)t2 * BU_ + (size_t)row * U_ + ((w - 2) * 16) * 16;
            load_llc<16>(fB, hbB, koff);
            haveB = true;
        } else if (w < 2 && t2 > 0) {
            // U2 half: h2[t2-1] — fire now, validate at phase B (slack).
            hbB = h2h + (size_t)(t2 - 1) * BU_ + (size_t)row * U_ + (w * 16) * 16;
            load_llc<16>(fB, hbB, koff);
            haveB = true;
        }

        // ================= phase A : layer-1 step t = k =================
        if (k < T_) {
            if (nA > 0) {
                if (w == 0)      wait_fresh<5>(fA, hbA, koff);
                else             wait_fresh<9>(fA, hbA, koff);
                if (w >= 2)      wait_fresh<16>(fB, hbB, koff);  // same vintage
                if (w == 0) {
                    #pragma unroll
                    for (int i = 0; i < 5; ++i) {
                        dep8(fA[i]);
                        accA0 = MFMA32(fA[i], a1f0[4 + i], accA0);
                        accA1 = MFMA32(fA[i], a1f1[4 + i], accA1);
                    }
                } else {
                    #pragma unroll
                    for (int i = 0; i < 9; ++i) {
                        dep8(fA[i]);
                        accA0 = MFMA32(fA[i], a1f0[i], accA0);
                        accA1 = MFMA32(fA[i], a1f1[i], accA1);
                    }
                }
            }

            // D layout: col=lane&31, row=(r&3)+8*(r>>2)+4*(lane>>5)
            #pragma unroll
            for (int r = 0; r < 16; ++r) {
                int rr = (r & 3) + 8 * (r >> 2) + 4 * (lane >> 5);
                red[w][0][rr][arow] = accA0[r];
                red[w][1][rr][arow] = accA1[r];
            }
            __syncthreads();

            {   // epilogue: 256 thr = 32 rows x 8 unit-pairs; one u32 sys store
                int u2 = (tid & 7) * 2;
                int r  = tid >> 3;
                unsigned int pk = 0;
                #pragma unroll
                for (int du = 0; du < 2; ++du) {
                    int u = u2 + du;
                    float zi = 0.f, zf = 0.f, zg = 0.f, zo = 0.f;
                    #pragma unroll
                    for (int ww = 0; ww < 4; ++ww) {
                        zi += red[ww][0][r][u];
                        zf += red[ww][0][r][16 + u];
                        zg += red[ww][1][r][u];
                        zo += red[ww][1][r][16 + u];
                    }
                    zi += bias1_s[u];      zf += bias1_s[16 + u];
                    zg += bias1_s[32 + u]; zo += bias1_s[48 + u];
                    float si = 1.f / (1.f + __expf(-zi));
                    float sf = 1.f / (1.f + __expf(-zf));
                    float so = 1.f / (1.f + __expf(-zo));
                    float gg = zg > 0.f ? zg : 0.f;
                    float cn = sf * cst1[r][u] + si * gg;
                    cst1[r][u] = cn;
                    float hn = so * (cn > 0.f ? cn : 0.f);
                    pk |= ((unsigned int)f2bf(hn)) << (16 * du);
                }
                unsigned int* hp = (unsigned int*)(h1h + (size_t)k * BU_
                                   + (size_t)(mo * 32 + r) * U_ + ug * 16 + u2);
                sys_store_u32(hp, pk);   // the store IS the signal
            }
            __syncthreads();
        }

        // ================= phase B : layer-2 step t2 = k-1 =================
        if (k >= 1) {
            floatx16 acc0, acc1;
            #pragma unroll
            for (int i = 0; i < 16; ++i) { acc0[i] = 0.f; acc1[i] = 0.f; }

            if (haveB) {
                // ALL waves re-validate here. Steady state: fresh already
                // (w>=2 validated in phase A) -> immediate exit. Covers the
                // k=T_ path where phase A is skipped (r5's race).
                wait_fresh<16>(fB, hbB, koff);
                #pragma unroll
                for (int i = 0; i < 16; ++i) {
                    dep8(fB[i]);
                    acc0 = MFMA32(fB[i], b2f0[i], acc0);
                    acc1 = MFMA32(fB[i], b2f1[i], acc1);
                }
            }

            #pragma unroll
            for (int r = 0; r < 16; ++r) {
                int rr = (r & 3) + 8 * (r >> 2) + 4 * (lane >> 5);
                red[w][0][rr][arow] = acc0[r];
                red[w][1][rr][arow] = acc1[r];
            }
            __syncthreads();

            {
                int u2 = (tid & 7) * 2;
                int r  = tid >> 3;
                unsigned int pk = 0;
                #pragma unroll
                for (int du = 0; du < 2; ++du) {
                    int u = u2 + du;
                    float zi = 0.f, zf = 0.f, zg = 0.f, zo = 0.f;
                    #pragma unroll
                    for (int ww = 0; ww < 4; ++ww) {
                        zi += red[ww][0][r][u];
                        zf += red[ww][0][r][16 + u];
                        zg += red[ww][1][r][u];
                        zo += red[ww][1][r][16 + u];
                    }
                    zi += bias2_s[u];      zf += bias2_s[16 + u];
                    zg += bias2_s[32 + u]; zo += bias2_s[48 + u];
                    float si = 1.f / (1.f + __expf(-zi));
                    float sf = 1.f / (1.f + __expf(-zf));
                    float so = 1.f / (1.f + __expf(-zo));
                    float gg = zg > 0.f ? zg : 0.f;
                    float cn = sf * cst2[r][u] + si * gg;
                    cst2[r][u] = cn;
                    float hn = so * (cn > 0.f ? cn : 0.f);
                    pk |= ((unsigned int)f2bf(hn)) << (16 * du);
                }
                unsigned int* hp = (unsigned int*)(h2h + (size_t)t2 * BU_
                                   + (size_t)(mo * 32 + r) * U_ + ug * 16 + u2);
                sys_store_u32(hp, pk);
            }
            __syncthreads();
        }
    }
}

__global__ void dense_kernel(const unsigned short* __restrict__ h2,
                             const float* __restrict__ Wd,
                             const float* __restrict__ bd,
                             float* __restrict__ out) {
    int b = blockIdx.x;
    int lane = threadIdx.x;                  // 64 lanes
    const unsigned short* hp = h2 + (long)b * U_ + lane * 8;
    short8 v = llc_load(hp);                 // LLC-coherent: no stale-L2 risk
    VMWAIT(0);
    __builtin_amdgcn_sched_barrier(0);
    dep8(v);
    float sum = 0.f;
    #pragma unroll
    for (int j = 0; j < 8; ++j) sum += bf2f((unsigned short)v[j]) * Wd[lane * 8 + j];
    #pragma unroll
    for (int off = 32; off; off >>= 1) sum += __shfl_down(sum, off);
    if (lane == 0) out[b] = 1.f / (1.f + __expf(-(sum + bd[0])));
}

extern "C" void kernel_launch(void* const* d_in, const int* in_sizes, int n_in,
                              void* d_out, int out_size, void* d_ws, size_t ws_size,
                              hipStream_t stream) {
    const float* x  = (const float*)d_in[0];
    const float* W1 = (const float*)d_in[1];
    const float* U1 = (const float*)d_in[2];
    const float* b1 = (const float*)d_in[3];
    const float* W2 = (const float*)d_in[4];
    const float* U2 = (const float*)d_in[5];
    const float* b2 = (const float*)d_in[6];
    const float* Wd = (const float*)d_in[7];
    const float* bd = (const float*)d_in[8];
    float* out = (float*)d_out;

    char* ws = (char*)d_ws;
    size_t off = 0;
    unsigned short* xb  = (unsigned short*)(ws + off); off += (size_t)B_ * T_ * F_ * 2;      // 8.39 MB
    unsigned short* P1  = (unsigned short*)(ws + off); off += (size_t)32 * 2 * 36 * 512 * 2; // 2.36 MB
    unsigned short* P2  = (unsigned short*)(ws + off); off += (size_t)32 * 2 * 64 * 512 * 2; // 4.19 MB
    unsigned short* h1h = (unsigned short*)(ws + off); off += (size_t)T_ * BU_ * 2;          // 67.1 MB
    unsigned short* h2h = (unsigned short*)(ws + off); off += (size_t)T_ * BU_ * 2;          // 67.1 MB

    int n = B_ * T_ * F_;
    cast_x_kernel<<<(n + 255) / 256, 256, 0, stream>>>(x, xb, n);
    {
        long tot1 = 32L * 2 * 36 * 512;
        pack32_kernel<<<(int)((tot1 + 255) / 256), 256, 0, stream>>>(W1, U1, P1, 36, 64);
        long tot2 = 32L * 2 * 64 * 512;
        pack32_kernel<<<(int)((tot2 + 255) / 256), 256, 0, stream>>>(W2, U2, P2, 64, 512);
    }
    // Poison steps 0,1 via system-scope stores (no host memset anywhere).
    poison01_kernel<<<(2 * (BU_ / 2) + 255) / 256, 256, 0, stream>>>(h1h, h2h);

    // 256 blocks = 1 block/CU: co-residency guaranteed, plain launch.
    lstm_persist<<<256, 256, 0, stream>>>(xb, P1, P2, b1, b2, h1h, h2h);

    dense_kernel<<<B_, 64, 0, stream>>>(h2h + (size_t)(T_ - 1) * BU_,
                                        Wd, bd, out);
}

// Round 9
// 1741.233 us; speedup vs baseline: 68.6801x; 1.1704x over previous
//
#include <hip/hip_runtime.h>
#include <hip/hip_bf16.h>

#define B_  256
#define T_  256
#define F_  64
#define U_  512
#define NG_ 2048   // 4*U
#define BU_ (B_ * U_)

typedef __attribute__((ext_vector_type(8))) short short8;
typedef __attribute__((ext_vector_type(16))) float floatx16;

__device__ __forceinline__ unsigned short f2bf(float f) {
    union { float f; unsigned int u; } v; v.f = f;
    unsigned int u = v.u;
    return (unsigned short)((u + 0x7FFFu + ((u >> 16) & 1u)) >> 16);
}
__device__ __forceinline__ float bf2f(unsigned short s) {
    union { unsigned int u; float f; } v; v.u = ((unsigned int)s) << 16;
    return v.f;
}

__global__ void cast_x_kernel(const float* __restrict__ x,
                              unsigned short* __restrict__ xb, int n) {
    int i = blockIdx.x * blockDim.x + threadIdx.x;
    if (i < n) xb[i] = f2bf(x[i]);
}

// Pack weights into 32x32x16 MFMA B-fragments, per unit-group (16 units -> 64
// block-local gate cols = 2 n32 tiles: [i16|f16] [g16|o16]).
__global__ void pack32_kernel(const float* __restrict__ W, const float* __restrict__ Uw,
                              unsigned short* __restrict__ dst, int KT, int KX) {
    long tid = (long)blockIdx.x * blockDim.x + threadIdx.x;
    long total = 32L * 2 * KT * 512;
    if (tid >= total) return;
    int j    = (int)(tid & 7);
    int lane = (int)((tid >> 3) & 63);
    int p512 = (int)(tid >> 9);
    int kt   = p512 % KT;
    int q    = p512 / KT;
    int nt   = q & 1;
    int ug   = q >> 1;
    int c    = nt * 32 + (lane & 31);
    int srcn = (c >> 4) * U_ + ug * 16 + (c & 15);
    int k    = kt * 16 + (lane >> 5) * 8 + j;
    float v  = (k < KX) ? W[(long)k * NG_ + srcn] : Uw[(long)(k - KX) * NG_ + srcn];
    dst[tid] = f2bf(v);
}

// LLC-coherent 16-B load (system scope): r0/r2-proven across blocks.
__device__ __forceinline__ short8 llc_load(const unsigned short* p) {
    short8 r;
    asm volatile("global_load_dwordx4 %0, %1, off sc0 sc1" : "=v"(r) : "v"(p));
    return r;
}
#define VMWAIT(N) asm volatile("s_waitcnt vmcnt(" #N ")" ::: "memory")
__device__ __forceinline__ void dep8(short8& x) { asm volatile("" : "+v"(x)); }

#define MFMA32(a, b, c) __builtin_amdgcn_mfma_f32_32x32x16_bf16(a, b, c, 0, 0, 0)

// Poll all 32 producer flag lines of this mo-group (r0-proven primitive).
// Lane l watches line (l&31); done when every producer's flag >= tgt.
__device__ __forceinline__ void wait_all(const int* f, int tgt, int lane) {
    const int* p = f + (lane & 31) * 32;   // one 128-B line per producer
    int guard = 0;
    for (;;) {
        int v = __hip_atomic_load(p, __ATOMIC_RELAXED, __HIP_MEMORY_SCOPE_AGENT);
        if (__ballot(v >= tgt) == ~0ull) break;
        __builtin_amdgcn_s_sleep(1);
        if (++guard > (1 << 19)) break;   // fail visibly, never hang
    }
}

// Persistent 2-layer LSTM. 256 blocks x 256 thr = 1 block/CU.
// iter k: phase A = L1 step k, phase B = L2 step k-1. Weights in VGPRs.
// SINGLE exchange per iteration: flag[ug] = k+1 means "this block finished
// iter k" => h1[k] AND h2[k-1] visible. Top-of-iter wait: all peers >= k,
// which covers BOTH phase A's h1[k-1] and phase B's h1[k-1]/h2[k-2].
// vs r0: one exposed latency window per iter instead of two, 4 barriers
// instead of 5, epilogue-A overlapped with phase-B MFMA latency (redA/redB).
// WAR (4-deep rings): flag>=k => peers started iter k => long past reading
// the slots h1[k-4]/h2[k-5] that iter k overwrites.
__global__ __launch_bounds__(256, 1) void lstm_persist(
    const unsigned short* __restrict__ xb,
    const unsigned short* __restrict__ P1,
    const unsigned short* __restrict__ P2,
    const float* __restrict__ b1, const float* __restrict__ b2,
    unsigned short* __restrict__ h1r, unsigned short* __restrict__ h2r,
    int* flags)
{
    const int bid  = blockIdx.x;     // 0..255
    const int mo   = bid & 7;        // m-octile (row-slab group)
    const int ug   = bid >> 3;       // 32 unit-groups of 16 units
    const int tid  = threadIdx.x;
    const int w    = tid >> 6;       // wave 0..3 (k-split)
    const int lane = tid & 63;
    const int arow = lane & 31;
    const int koff = (lane >> 5) * 8;
    const int row  = mo * 32 + arow;

    int* fl = flags + mo * 32 * 32;  // 32 lines (128 B each) per mo-group

    __shared__ float redA[4][2][32][33];
    __shared__ float redB[4][2][32][33];
    __shared__ float cst1[32][16];
    __shared__ float cst2[32][16];
    __shared__ float bias1_s[64], bias2_s[64];

    for (int i = tid; i < 512; i += 256) {
        cst1[i >> 4][i & 15] = 0.f;
        cst2[i >> 4][i & 15] = 0.f;
    }
    if (tid < 64) {
        bias1_s[tid] = b1[(tid >> 4) * U_ + ug * 16 + (tid & 15)];
        bias2_s[tid] = b2[(tid >> 4) * U_ + ug * 16 + (tid & 15)];
    }

    // ---- load BOTH layers' B-fragments into registers (once) ----
    short8 a1f0[9], a1f1[9];     // L1: 36 ktiles of K=16, 9 per wave
    {
        const unsigned short* base = P1 + (size_t)ug * (2 * 36 * 512);
        #pragma unroll
        for (int i = 0; i < 9; ++i) {
            a1f0[i] = *(const short8*)(base + ((size_t)(0 * 36 + w * 9 + i) * 64 + lane) * 8);
            a1f1[i] = *(const short8*)(base + ((size_t)(1 * 36 + w * 9 + i) * 64 + lane) * 8);
        }
    }
    short8 b2f0[16], b2f1[16];   // L2: 64 ktiles; w0,w1 -> U2 half; w2,w3 -> W2 half
    {
        const unsigned short* base = P2 + (size_t)ug * (2 * 64 * 512);
        const int fb = (w < 2) ? (32 + w * 16) : ((w - 2) * 16);
        #pragma unroll
        for (int i = 0; i < 16; ++i) {
            b2f0[i] = *(const short8*)(base + ((size_t)(0 * 64 + fb + i) * 64 + lane) * 8);
            b2f1[i] = *(const short8*)(base + ((size_t)(1 * 64 + fb + i) * 64 + lane) * 8);
        }
    }
    __syncthreads();

    for (int k = 0; k <= T_; ++k) {
        const int t2 = k - 1;
        floatx16 accA0, accA1;
        #pragma unroll
        for (int i = 0; i < 16; ++i) { accA0[i] = 0.f; accA1[i] = 0.f; }

        // ---- pre-barrier: w0 computes x-part (flag-free), w3 polls flags ----
        if (w == 0) {
            if (k < T_) {
                const unsigned short* xbase = xb + ((size_t)row * T_ + k) * F_;
                #pragma unroll
                for (int i = 0; i < 4; ++i) {
                    short8 a = *(const short8*)(xbase + i * 16 + koff);
                    accA0 = MFMA32(a, a1f0[i], accA0);
                    accA1 = MFMA32(a, a1f1[i], accA1);
                }
            }
        } else if (w == 3) {
            if (k >= 1) wait_all(fl, k, lane);   // peers finished iter k-1
        }
        __syncthreads();
        __atomic_signal_fence(__ATOMIC_ACQUIRE);

        // ---- issue ALL of this iteration's h loads, batched ----
        short8 fA[9];
        const int nA = (k > 0 && k < T_) ? ((w == 0) ? 5 : 9) : 0;
        if (nA) {
            const unsigned short* hb = h1r + (size_t)((k - 1) & 3) * BU_
                                       + (size_t)row * U_
                                       + ((w == 0) ? 0 : (w * 9 - 4) * 16);
            if (w == 0) {
                #pragma unroll
                for (int i = 0; i < 5; ++i) fA[i] = llc_load(hb + i * 16 + koff);
            } else {
                #pragma unroll
                for (int i = 0; i < 9; ++i) fA[i] = llc_load(hb + i * 16 + koff);
            }
        }
        short8 fB[16];
        bool haveB = false;
        if (k >= 1 && w >= 2) {
            // W2 half: h1[t2] = h1[k-1] (covered by the top wait)
            const unsigned short* hb = h1r + (size_t)(t2 & 3) * BU_
                                       + (size_t)row * U_ + ((w - 2) * 16) * 16;
            #pragma unroll
            for (int i = 0; i < 16; ++i) fB[i] = llc_load(hb + i * 16 + koff);
            haveB = true;
        } else if (w < 2 && t2 > 0) {
            // U2 half: h2[t2-1] = h2[k-2] (ALSO covered by the top wait)
            const unsigned short* hb = h2r + (size_t)((t2 - 1) & 3) * BU_
                                       + (size_t)row * U_ + (w * 16) * 16;
            #pragma unroll
            for (int i = 0; i < 16; ++i) fB[i] = llc_load(hb + i * 16 + koff);
            haveB = true;
        }

        // ================= phase A : layer-1 step t = k =================
        if (k < T_) {
            if (nA > 0) {
                if (haveB) { VMWAIT(16); } else { VMWAIT(0); }
                if (w == 0) {
                    #pragma unroll
                    for (int i = 0; i < 5; ++i) {
                        dep8(fA[i]);
                        accA0 = MFMA32(fA[i], a1f0[4 + i], accA0);
                        accA1 = MFMA32(fA[i], a1f1[4 + i], accA1);
                    }
                } else {
                    #pragma unroll
                    for (int i = 0; i < 9; ++i) {
                        dep8(fA[i]);
                        accA0 = MFMA32(fA[i], a1f0[i], accA0);
                        accA1 = MFMA32(fA[i], a1f1[i], accA1);
                    }
                }
            }
            // D layout: col=lane&31, row=(r&3)+8*(r>>2)+4*(lane>>5)
            #pragma unroll
            for (int r = 0; r < 16; ++r) {
                int rr = (r & 3) + 8 * (r >> 2) + 4 * (lane >> 5);
                redA[w][0][rr][arow] = accA0[r];
                redA[w][1][rr][arow] = accA1[r];
            }
        }
        __syncthreads();   // redA complete (no-op content at k==T_)

        // ====== overlap region: phase-B MFMAs + epilogue A ======
        floatx16 acc0, acc1;
        #pragma unroll
        for (int i = 0; i < 16; ++i) { acc0[i] = 0.f; acc1[i] = 0.f; }
        if (k >= 1 && haveB) {
            VMWAIT(0);
            #pragma unroll
            for (int i = 0; i < 16; ++i) {
                dep8(fB[i]);
                acc0 = MFMA32(fB[i], b2f0[i], acc0);
                acc1 = MFMA32(fB[i], b2f1[i], acc1);
            }
        }
        if (k < T_) {   // epilogue A (VALU) hides under B's MFMA latency
            int u2 = (tid & 7) * 2;
            int r  = tid >> 3;
            unsigned int pk = 0;
            #pragma unroll
            for (int du = 0; du < 2; ++du) {
                int u = u2 + du;
                float zi = 0.f, zf = 0.f, zg = 0.f, zo = 0.f;
                #pragma unroll
                for (int ww = 0; ww < 4; ++ww) {
                    zi += redA[ww][0][r][u];
                    zf += redA[ww][0][r][16 + u];
                    zg += redA[ww][1][r][u];
                    zo += redA[ww][1][r][16 + u];
                }
                zi += bias1_s[u];      zf += bias1_s[16 + u];
                zg += bias1_s[32 + u]; zo += bias1_s[48 + u];
                float si = 1.f / (1.f + __expf(-zi));
                float sf = 1.f / (1.f + __expf(-zf));
                float so = 1.f / (1.f + __expf(-zo));
                float gg = zg > 0.f ? zg : 0.f;
                float cn = sf * cst1[r][u] + si * gg;
                cst1[r][u] = cn;
                float hn = so * (cn > 0.f ? cn : 0.f);
                pk |= ((unsigned int)f2bf(hn)) << (16 * du);
            }
            unsigned int* hp = (unsigned int*)(h1r + (size_t)(k & 3) * BU_
                               + (size_t)(mo * 32 + r) * U_ + ug * 16 + u2);
            __hip_atomic_store(hp, pk, __ATOMIC_RELAXED, __HIP_MEMORY_SCOPE_AGENT);
        }
        if (k >= 1) {
            #pragma unroll
            for (int r = 0; r < 16; ++r) {
                int rr = (r & 3) + 8 * (r >> 2) + 4 * (lane >> 5);
                redB[w][0][rr][arow] = acc0[r];
                redB[w][1][rr][arow] = acc1[r];
            }
        }
        __syncthreads();   // redB complete + epilogue-A reads of redA done

        // ================= epilogue B : layer-2 step t2 = k-1 ============
        if (k >= 1) {
            int u2 = (tid & 7) * 2;
            int r  = tid >> 3;
            unsigned int pk = 0;
            #pragma unroll
            for (int du = 0; du < 2; ++du) {
                int u = u2 + du;
                float zi = 0.f, zf = 0.f, zg = 0.f, zo = 0.f;
                #pragma unroll
                for (int ww = 0; ww < 4; ++ww) {
                    zi += redB[ww][0][r][u];
                    zf += redB[ww][0][r][16 + u];
                    zg += redB[ww][1][r][u];
                    zo += redB[ww][1][r][16 + u];
                }
                zi += bias2_s[u];      zf += bias2_s[16 + u];
                zg += bias2_s[32 + u]; zo += bias2_s[48 + u];
                float si = 1.f / (1.f + __expf(-zi));
                float sf = 1.f / (1.f + __expf(-zf));
                float so = 1.f / (1.f + __expf(-zo));
                float gg = zg > 0.f ? zg : 0.f;
                float cn = sf * cst2[r][u] + si * gg;
                cst2[r][u] = cn;
                float hn = so * (cn > 0.f ? cn : 0.f);
                pk |= ((unsigned int)f2bf(hn)) << (16 * du);
            }
            unsigned int* hp = (unsigned int*)(h2r + (size_t)(t2 & 3) * BU_
                               + (size_t)(mo * 32 + r) * U_ + ug * 16 + u2);
            __hip_atomic_store(hp, pk, __ATOMIC_RELAXED, __HIP_MEMORY_SCOPE_AGENT);
        }
        __syncthreads();   // drains vmcnt(0): h1[k] AND h2[k-1] committed
        __atomic_signal_fence(__ATOMIC_RELEASE);
        if (tid == 0)
            __hip_atomic_store(fl + ug * 32, k + 1, __ATOMIC_RELAXED,
                               __HIP_MEMORY_SCOPE_AGENT);
    }
}

__global__ void dense_kernel(const unsigned short* __restrict__ h2,
                             const float* __restrict__ Wd,
                             const float* __restrict__ bd,
                             float* __restrict__ out) {
    int b = blockIdx.x;
    int lane = threadIdx.x;                  // 64 lanes
    const unsigned short* hp = h2 + (long)b * U_ + lane * 8;
    float sum = 0.f;
    #pragma unroll
    for (int j = 0; j < 8; ++j) sum += bf2f(hp[j]) * Wd[lane * 8 + j];
    #pragma unroll
    for (int off = 32; off; off >>= 1) sum += __shfl_down(sum, off);
    if (lane == 0) out[b] = 1.f / (1.f + __expf(-(sum + bd[0])));
}

extern "C" void kernel_launch(void* const* d_in, const int* in_sizes, int n_in,
                              void* d_out, int out_size, void* d_ws, size_t ws_size,
                              hipStream_t stream) {
    const float* x  = (const float*)d_in[0];
    const float* W1 = (const float*)d_in[1];
    const float* U1 = (const float*)d_in[2];
    const float* b1 = (const float*)d_in[3];
    const float* W2 = (const float*)d_in[4];
    const float* U2 = (const float*)d_in[5];
    const float* b2 = (const float*)d_in[6];
    const float* Wd = (const float*)d_in[7];
    const float* bd = (const float*)d_in[8];
    float* out = (float*)d_out;

    char* ws = (char*)d_ws;
    size_t off = 0;
    unsigned short* xb  = (unsigned short*)(ws + off); off += (size_t)B_ * T_ * F_ * 2;      // 8.39 MB
    unsigned short* P1  = (unsigned short*)(ws + off); off += (size_t)32 * 2 * 36 * 512 * 2; // 2.36 MB
    unsigned short* P2  = (unsigned short*)(ws + off); off += (size_t)32 * 2 * 64 * 512 * 2; // 4.19 MB
    unsigned short* h1r = (unsigned short*)(ws + off); off += (size_t)4 * BU_ * 2;           // 1 MB
    unsigned short* h2r = (unsigned short*)(ws + off); off += (size_t)4 * BU_ * 2;           // 1 MB
    int* flags = (int*)(ws + off); off += (size_t)8 * 32 * 32 * 4;   // 32 KB (128B/flag line)

    (void)hipMemsetAsync(flags, 0, (size_t)8 * 32 * 32 * 4, stream);

    int n = B_ * T_ * F_;
    cast_x_kernel<<<(n + 255) / 256, 256, 0, stream>>>(x, xb, n);
    {
        long tot1 = 32L * 2 * 36 * 512;
        pack32_kernel<<<(int)((tot1 + 255) / 256), 256, 0, stream>>>(W1, U1, P1, 36, 64);
        long tot2 = 32L * 2 * 64 * 512;
        pack32_kernel<<<(int)((tot2 + 255) / 256), 256, 0, stream>>>(W2, U2, P2, 64, 512);
    }

    // 256 blocks = 1 block/CU: co-residency guaranteed, plain launch.
    lstm_persist<<<256, 256, 0, stream>>>(xb, P1, P2, b1, b2, h1r, h2r, flags);

    dense_kernel<<<B_, 64, 0, stream>>>(h2r + (size_t)((T_ - 1) & 3) * BU_,
                                        Wd, bd, out);
}

// Round 10
// 1282.056 us; speedup vs baseline: 93.2784x; 1.3582x over previous
//
#include <hip/hip_runtime.h>
#include <hip/hip_bf16.h>

#define B_  256
#define T_  256
#define F_  64
#define U_  512
#define NG_ 2048   // 4*U
#define BU_ (B_ * U_)

typedef __attribute__((ext_vector_type(8))) short short8;
typedef __attribute__((ext_vector_type(16))) float floatx16;

__device__ __forceinline__ unsigned short f2bf(float f) {
    union { float f; unsigned int u; } v; v.f = f;
    unsigned int u = v.u;
    return (unsigned short)((u + 0x7FFFu + ((u >> 16) & 1u)) >> 16);
}
__device__ __forceinline__ float bf2f(unsigned short s) {
    union { unsigned int u; float f; } v; v.u = ((unsigned int)s) << 16;
    return v.f;
}

__global__ void cast_x_kernel(const float* __restrict__ x,
                              unsigned short* __restrict__ xb, int n) {
    int i = blockIdx.x * blockDim.x + threadIdx.x;
    if (i < n) xb[i] = f2bf(x[i]);
}

// Pack weights into 32x32x16 MFMA B-fragments.
// Layout: [ug=16][tile q=4 (gate i,f,g,o)][ktile=KT][512 shorts].
// Tile q covers units ug*32..ug*32+31 of gate q (source col q*U + unit).
// Fragment: lane&31 = col(unit), k-row = (lane>>5)*8 + j.
__global__ void pack32_kernel(const float* __restrict__ W, const float* __restrict__ Uw,
                              unsigned short* __restrict__ dst, int KT, int KX) {
    long tid = (long)blockIdx.x * blockDim.x + threadIdx.x;
    long total = 16L * 4 * KT * 512;
    if (tid >= total) return;
    int j    = (int)(tid & 7);
    int lane = (int)((tid >> 3) & 63);
    int p512 = (int)(tid >> 9);
    int kt   = p512 % KT;
    int q    = (p512 / KT) & 3;
    int ug   = p512 / (KT * 4);
    int srcn = q * U_ + ug * 32 + (lane & 31);
    int k    = kt * 16 + (lane >> 5) * 8 + j;
    float v  = (k < KX) ? W[(long)k * NG_ + srcn] : Uw[(long)(k - KX) * NG_ + srcn];
    dst[tid] = f2bf(v);
}

// LLC-coherent 16-B load (system scope): proven across blocks (r0/r2/r9).
__device__ __forceinline__ short8 llc_load(const unsigned short* p) {
    short8 r;
    asm volatile("global_load_dwordx4 %0, %1, off sc0 sc1" : "=v"(r) : "v"(p));
    return r;
}
#define VMWAIT(N) asm volatile("s_waitcnt vmcnt(" #N ")" ::: "memory")
__device__ __forceinline__ void dep8(short8& x) { asm volatile("" : "+v"(x)); }

#define MFMA32(a, b, c) __builtin_amdgcn_mfma_f32_32x32x16_bf16(a, b, c, 0, 0, 0)

// Dual-group poll: lanes 0-31 watch the 16 flagsA lines (target ta), lanes
// 32-63 the 16 flagsB lines (target tb). Targets <= 0 are auto-true.
__device__ __forceinline__ void wait_dual(const int* fa, int ta,
                                          const int* fb, int tb, int lane) {
    const int* p  = (lane < 32) ? (fa + (lane & 15) * 32) : (fb + (lane & 15) * 32);
    const int tgt = (lane < 32) ? ta : tb;
    int guard = 0;
    for (;;) {
        int v = __hip_atomic_load(p, __ATOMIC_RELAXED, __HIP_MEMORY_SCOPE_AGENT);
        if (__ballot(v >= tgt) == ~0ull) break;
        __builtin_amdgcn_s_sleep(1);
        if (++guard > (1 << 19)) break;   // fail visibly, never hang
    }
}

// Persistent 2-layer LSTM, LAYER-SPLIT PIPELINE.
// Blocks 0-127 = layer 1, blocks 128-255 = layer 2, concurrent on separate
// CUs (139KB LDS forces 1 block/CU -> all 256 resident). Each block: 32 rows
// (mo) x 32 units (ug of 16), 8 waves, K-split across waves, LDS reduce.
// Chains: fA[mo][ug]=k+1 after L1 iter k (h1[k] committed); fB likewise for
// L2. L1(k) waits fA>=k (peers' h1[k-1]) and fB>=k-3 (L2 done reading the
// h1 ring slot being overwritten). L2(t) waits fA>=t+1 (h1[t]) and fB>=t
// (peers' h2[t-1]). Joint induction: no cycle; 4-deep rings covered.
// Each chain's period = its own half-size iteration instead of the full
// A+B iteration of the single-block design (r9: 6.8us).
__global__ __launch_bounds__(512, 1) void lstm_persist(
    const unsigned short* __restrict__ xb,
    const unsigned short* __restrict__ P1,
    const unsigned short* __restrict__ P2,
    const float* __restrict__ b1, const float* __restrict__ b2,
    unsigned short* __restrict__ h1r, unsigned short* __restrict__ h2r,
    int* flagsA, int* flagsB)
{
    const int bid  = blockIdx.x;
    const bool isL1 = (bid < 128);
    const int sub  = isL1 ? bid : (bid - 128);
    const int mo   = sub & 7;        // row-slab (32 rows)
    const int ug   = sub >> 3;       // 0..15: unit-group of 32 units
    const int tid  = threadIdx.x;
    const int w    = tid >> 6;       // wave 0..7
    const int lane = tid & 63;
    const int arow = lane & 31;
    const int koff = (lane >> 5) * 8;
    const int row  = mo * 32 + arow;

    int* fA_ = flagsA + mo * 16 * 32;   // 16 lines (128B) per mo
    int* fB_ = flagsB + mo * 16 * 32;

    __shared__ float red[8][4][32][33];   // 8 waves x 4 gate-tiles partials
    __shared__ float cst[32][32];         // cell state (rows x units)
    __shared__ float bias_s[4][32];

    for (int i = tid; i < 1024; i += 512) cst[i >> 5][i & 31] = 0.f;
    if (tid < 128) {
        const float* bb = isL1 ? b1 : b2;
        bias_s[tid >> 5][tid & 31] = bb[(tid >> 5) * U_ + ug * 32 + (tid & 31)];
    }

    if (isL1) {
        // ---------------- LAYER-1 pipeline ----------------
        // ktiles 0..35 (0-3 = x, 4-35 = h1). w0:0-4, w1:5-9, w2:10-14,
        // w3:15-19, w4:20-23, w5:24-27, w6:28-31, w7:32-35.
        const int kbase = (w < 4) ? w * 5 : 20 + (w - 4) * 4;
        const int kcnt  = (w < 4) ? 5 : 4;
        short8 wf[4][5];
        {
            const unsigned short* base = P1 + (size_t)ug * (4 * 36 * 512);
            #pragma unroll
            for (int q = 0; q < 4; ++q) {
                #pragma unroll
                for (int i = 0; i < 5; ++i) {
                    if (i < kcnt)
                        wf[q][i] = *(const short8*)(base
                            + ((size_t)(q * 36 + kbase + i) * 64 + lane) * 8);
                }
            }
        }
        __syncthreads();

        for (int k = 0; k < T_; ++k) {
            floatx16 acc[4];
            #pragma unroll
            for (int q = 0; q < 4; ++q) {
                #pragma unroll
                for (int i = 0; i < 16; ++i) acc[q][i] = 0.f;
            }

            // pre-barrier: w0 = x-part (flag-free), w7 = poll
            if (w == 0) {
                const unsigned short* xbase = xb + ((size_t)row * T_ + k) * F_;
                #pragma unroll
                for (int g = 0; g < 4; ++g) {
                    short8 a = *(const short8*)(xbase + g * 16 + koff);
                    #pragma unroll
                    for (int q = 0; q < 4; ++q) acc[q] = MFMA32(a, wf[q][g], acc[q]);
                }
            } else if (w == 7) {
                if (k >= 1) wait_dual(fA_, k, fB_, k - 3, lane);
            }
            __syncthreads();
            __atomic_signal_fence(__ATOMIC_ACQUIRE);

            if (k >= 1) {
                if (w == 0) {
                    // single h ktile (global 4 -> units 0-15), weight slot 4
                    const unsigned short* hb = h1r + (size_t)((k - 1) & 3) * BU_
                                               + (size_t)row * U_;
                    short8 fa0 = llc_load(hb + koff);
                    VMWAIT(0);
                    dep8(fa0);
                    #pragma unroll
                    for (int q = 0; q < 4; ++q) acc[q] = MFMA32(fa0, wf[q][4], acc[q]);
                } else {
                    const unsigned short* hb = h1r + (size_t)((k - 1) & 3) * BU_
                                               + (size_t)row * U_ + (kbase - 4) * 16;
                    short8 fa[5];
                    #pragma unroll
                    for (int i = 0; i < 5; ++i)
                        if (i < kcnt) fa[i] = llc_load(hb + i * 16 + koff);
                    VMWAIT(0);
                    #pragma unroll
                    for (int i = 0; i < 5; ++i) {
                        if (i < kcnt) {
                            dep8(fa[i]);
                            #pragma unroll
                            for (int q = 0; q < 4; ++q)
                                acc[q] = MFMA32(fa[i], wf[q][i], acc[q]);
                        }
                    }
                }
            }

            // D layout: col=lane&31 (unit), row=(r&3)+8*(r>>2)+4*(lane>>5)
            #pragma unroll
            for (int r = 0; r < 16; ++r) {
                int rr = (r & 3) + 8 * (r >> 2) + 4 * (lane >> 5);
                #pragma unroll
                for (int q = 0; q < 4; ++q) red[w][q][rr][arow] = acc[q][r];
            }
            __syncthreads();

            {   // epilogue: 512 thr = 32 rows x 16 unit-pairs
                int r = tid >> 4, u2 = (tid & 15) * 2;
                unsigned int pk = 0;
                #pragma unroll
                for (int du = 0; du < 2; ++du) {
                    int u = u2 + du;
                    float zi = 0.f, zf = 0.f, zg = 0.f, zo = 0.f;
                    #pragma unroll
                    for (int ww = 0; ww < 8; ++ww) {
                        zi += red[ww][0][r][u];
                        zf += red[ww][1][r][u];
                        zg += red[ww][2][r][u];
                        zo += red[ww][3][r][u];
                    }
                    zi += bias_s[0][u]; zf += bias_s[1][u];
                    zg += bias_s[2][u]; zo += bias_s[3][u];
                    float si = 1.f / (1.f + __expf(-zi));
                    float sf = 1.f / (1.f + __expf(-zf));
                    float so = 1.f / (1.f + __expf(-zo));
                    float gg = zg > 0.f ? zg : 0.f;
                    float cn = sf * cst[r][u] + si * gg;
                    cst[r][u] = cn;
                    float hn = so * (cn > 0.f ? cn : 0.f);
                    pk |= ((unsigned int)f2bf(hn)) << (16 * du);
                }
                unsigned int* hp = (unsigned int*)(h1r + (size_t)(k & 3) * BU_
                                   + (size_t)(mo * 32 + (tid >> 4)) * U_ + ug * 32 + u2);
                __hip_atomic_store(hp, pk, __ATOMIC_RELAXED, __HIP_MEMORY_SCOPE_AGENT);
            }
            __syncthreads();   // drains vmcnt(0): h1[k] committed
            __atomic_signal_fence(__ATOMIC_RELEASE);
            if (tid == 0)
                __hip_atomic_store(fA_ + ug * 32, k + 1, __ATOMIC_RELAXED,
                                   __HIP_MEMORY_SCOPE_AGENT);
        }
    } else {
        // ---------------- LAYER-2 pipeline ----------------
        // ktiles 0..63: 0-31 = W2 (h1[t] input), 32-63 = U2 (h2[t-1]).
        // wave w: ktiles w*8..w*8+7 (w<4: pure h1; w>=4: pure h2).
        short8 wf[4][8];
        {
            const unsigned short* base = P2 + (size_t)ug * (4 * 64 * 512);
            #pragma unroll
            for (int q = 0; q < 4; ++q) {
                #pragma unroll
                for (int i = 0; i < 8; ++i)
                    wf[q][i] = *(const short8*)(base
                        + ((size_t)(q * 64 + w * 8 + i) * 64 + lane) * 8);
            }
        }
        __syncthreads();

        for (int t = 0; t < T_; ++t) {
            if (w == 7) wait_dual(fA_, t + 1, fB_, t, lane);
            __syncthreads();
            __atomic_signal_fence(__ATOMIC_ACQUIRE);

            floatx16 acc[4];
            #pragma unroll
            for (int q = 0; q < 4; ++q) {
                #pragma unroll
                for (int i = 0; i < 16; ++i) acc[q][i] = 0.f;
            }

            const bool isU2 = (w >= 4);
            if (!isU2 || t >= 1) {
                const unsigned short* hb = isU2
                    ? h2r + (size_t)((t - 1) & 3) * BU_ + (size_t)row * U_ + (w - 4) * 128
                    : h1r + (size_t)(t & 3) * BU_       + (size_t)row * U_ + w * 128;
                short8 fb[8];
                #pragma unroll
                for (int i = 0; i < 8; ++i) fb[i] = llc_load(hb + i * 16 + koff);
                VMWAIT(0);
                #pragma unroll
                for (int i = 0; i < 8; ++i) {
                    dep8(fb[i]);
                    #pragma unroll
                    for (int q = 0; q < 4; ++q) acc[q] = MFMA32(fb[i], wf[q][i], acc[q]);
                }
            }

            #pragma unroll
            for (int r = 0; r < 16; ++r) {
                int rr = (r & 3) + 8 * (r >> 2) + 4 * (lane >> 5);
                #pragma unroll
                for (int q = 0; q < 4; ++q) red[w][q][rr][arow] = acc[q][r];
            }
            __syncthreads();

            {   // epilogue
                int r = tid >> 4, u2 = (tid & 15) * 2;
                unsigned int pk = 0;
                #pragma unroll
                for (int du = 0; du < 2; ++du) {
                    int u = u2 + du;
                    float zi = 0.f, zf = 0.f, zg = 0.f, zo = 0.f;
                    #pragma unroll
                    for (int ww = 0; ww < 8; ++ww) {
                        zi += red[ww][0][r][u];
                        zf += red[ww][1][r][u];
                        zg += red[ww][2][r][u];
                        zo += red[ww][3][r][u];
                    }
                    zi += bias_s[0][u]; zf += bias_s[1][u];
                    zg += bias_s[2][u]; zo += bias_s[3][u];
                    float si = 1.f / (1.f + __expf(-zi));
                    float sf = 1.f / (1.f + __expf(-zf));
                    float so = 1.f / (1.f + __expf(-zo));
                    float gg = zg > 0.f ? zg : 0.f;
                    float cn = sf * cst[r][u] + si * gg;
                    cst[r][u] = cn;
                    float hn = so * (cn > 0.f ? cn : 0.f);
                    pk |= ((unsigned int)f2bf(hn)) << (16 * du);
                }
                unsigned int* hp = (unsigned int*)(h2r + (size_t)(t & 3) * BU_
                                   + (size_t)(mo * 32 + (tid >> 4)) * U_ + ug * 32 + u2);
                __hip_atomic_store(hp, pk, __ATOMIC_RELAXED, __HIP_MEMORY_SCOPE_AGENT);
            }
            __syncthreads();   // drains vmcnt(0): h2[t] committed
            __atomic_signal_fence(__ATOMIC_RELEASE);
            if (tid == 0)
                __hip_atomic_store(fB_ + ug * 32, t + 1, __ATOMIC_RELAXED,
                                   __HIP_MEMORY_SCOPE_AGENT);
        }
    }
}

__global__ void dense_kernel(const unsigned short* __restrict__ h2,
                             const float* __restrict__ Wd,
                             const float* __restrict__ bd,
                             float* __restrict__ out) {
    int b = blockIdx.x;
    int lane = threadIdx.x;                  // 64 lanes
    const unsigned short* hp = h2 + (long)b * U_ + lane * 8;
    float sum = 0.f;
    #pragma unroll
    for (int j = 0; j < 8; ++j) sum += bf2f(hp[j]) * Wd[lane * 8 + j];
    #pragma unroll
    for (int off = 32; off; off >>= 1) sum += __shfl_down(sum, off);
    if (lane == 0) out[b] = 1.f / (1.f + __expf(-(sum + bd[0])));
}

extern "C" void kernel_launch(void* const* d_in, const int* in_sizes, int n_in,
                              void* d_out, int out_size, void* d_ws, size_t ws_size,
                              hipStream_t stream) {
    const float* x  = (const float*)d_in[0];
    const float* W1 = (const float*)d_in[1];
    const float* U1 = (const float*)d_in[2];
    const float* b1 = (const float*)d_in[3];
    const float* W2 = (const float*)d_in[4];
    const float* U2 = (const float*)d_in[5];
    const float* b2 = (const float*)d_in[6];
    const float* Wd = (const float*)d_in[7];
    const float* bd = (const float*)d_in[8];
    float* out = (float*)d_out;

    char* ws = (char*)d_ws;
    size_t off = 0;
    unsigned short* xb  = (unsigned short*)(ws + off); off += (size_t)B_ * T_ * F_ * 2;      // 8.39 MB
    unsigned short* P1  = (unsigned short*)(ws + off); off += (size_t)16 * 4 * 36 * 512 * 2; // 2.36 MB
    unsigned short* P2  = (unsigned short*)(ws + off); off += (size_t)16 * 4 * 64 * 512 * 2; // 4.19 MB
    unsigned short* h1r = (unsigned short*)(ws + off); off += (size_t)4 * BU_ * 2;           // 1 MB
    unsigned short* h2r = (unsigned short*)(ws + off); off += (size_t)4 * BU_ * 2;           // 1 MB
    int* flagsA = (int*)(ws + off); off += (size_t)8 * 16 * 32 * 4;   // 16 KB
    int* flagsB = (int*)(ws + off); off += (size_t)8 * 16 * 32 * 4;   // 16 KB

    (void)hipMemsetAsync(flagsA, 0, (size_t)8 * 16 * 32 * 4 * 2, stream);

    int n = B_ * T_ * F_;
    cast_x_kernel<<<(n + 255) / 256, 256, 0, stream>>>(x, xb, n);
    {
        long tot1 = 16L * 4 * 36 * 512;
        pack32_kernel<<<(int)((tot1 + 255) / 256), 256, 0, stream>>>(W1, U1, P1, 36, 64);
        long tot2 = 16L * 4 * 64 * 512;
        pack32_kernel<<<(int)((tot2 + 255) / 256), 256, 0, stream>>>(W2, U2, P2, 64, 512);
    }

    // 256 blocks x 512 thr; 139KB LDS/block -> exactly 1 block/CU, all
    // resident. Blocks 0-127 = layer-1 pipeline, 128-255 = layer-2.
    lstm_persist<<<256, 512, 0, stream>>>(xb, P1, P2, b1, b2, h1r, h2r,
                                          flagsA, flagsB);

    dense_kernel<<<B_, 64, 0, stream>>>(h2r + (size_t)((T_ - 1) & 3) * BU_,
                                        Wd, bd, out);
}

// Round 11
// 1186.980 us; speedup vs baseline: 100.7499x; 1.0801x over previous
//
#include <hip/hip_runtime.h>
#include <hip/hip_bf16.h>

#define B_  256
#define T_  256
#define F_  64
#define U_  512
#define NG_ 2048   // 4*U
#define BU_ (B_ * U_)

typedef __attribute__((ext_vector_type(8))) short short8;
typedef __attribute__((ext_vector_type(16))) float floatx16;

__device__ __forceinline__ unsigned short f2bf(float f) {
    union { float f; unsigned int u; } v; v.f = f;
    unsigned int u = v.u;
    return (unsigned short)((u + 0x7FFFu + ((u >> 16) & 1u)) >> 16);
}
__device__ __forceinline__ float bf2f(unsigned short s) {
    union { unsigned int u; float f; } v; v.u = ((unsigned int)s) << 16;
    return v.f;
}

__global__ void cast_x_kernel(const float* __restrict__ x,
                              unsigned short* __restrict__ xb, int n) {
    int i = blockIdx.x * blockDim.x + threadIdx.x;
    if (i < n) xb[i] = f2bf(x[i]);
}

// Pack weights into 32x32x16 MFMA B-fragments.
// Layout: [ug=16][tile q=4 (gate i,f,g,o)][ktile=KT][512 shorts].
__global__ void pack32_kernel(const float* __restrict__ W, const float* __restrict__ Uw,
                              unsigned short* __restrict__ dst, int KT, int KX) {
    long tid = (long)blockIdx.x * blockDim.x + threadIdx.x;
    long total = 16L * 4 * KT * 512;
    if (tid >= total) return;
    int j    = (int)(tid & 7);
    int lane = (int)((tid >> 3) & 63);
    int p512 = (int)(tid >> 9);
    int kt   = p512 % KT;
    int q    = (p512 / KT) & 3;
    int ug   = p512 / (KT * 4);
    int srcn = q * U_ + ug * 32 + (lane & 31);
    int k    = kt * 16 + (lane >> 5) * 8 + j;
    float v  = (k < KX) ? W[(long)k * NG_ + srcn] : Uw[(long)(k - KX) * NG_ + srcn];
    dst[tid] = f2bf(v);
}

// LLC-coherent ops (system scope): proven across blocks (r0/r2/r6/r9/r10).
__device__ __forceinline__ short8 llc_load(const unsigned short* p) {
    short8 r;
    asm volatile("global_load_dwordx4 %0, %1, off sc0 sc1" : "=v"(r) : "v"(p));
    return r;
}
__device__ __forceinline__ void sys_store_u32(unsigned int* p, unsigned int v) {
    asm volatile("global_store_dword %0, %1, off sc0 sc1" :: "v"(p), "v"(v) : "memory");
}
#define VMWAIT(N) asm volatile("s_waitcnt vmcnt(" #N ")" ::: "memory")
__device__ __forceinline__ void dep8(short8& x) { asm volatile("" : "+v"(x)); }

#define MFMA32(a, b, c) __builtin_amdgcn_mfma_f32_32x32x16_bf16(a, b, c, 0, 0, 0)

// LDS-only barrier (HK 8-phase pattern): drain LDS ops, raw s_barrier.
// Global stores are NOT drained -> h-store LLC commit overlaps next iter's
// load flight (vs __syncthreads' implicit s_waitcnt vmcnt(0)).
__device__ __forceinline__ void lds_barrier() {
    __builtin_amdgcn_sched_barrier(0);
    asm volatile("s_waitcnt lgkmcnt(0)" ::: "memory");
    __builtin_amdgcn_s_barrier();
    __builtin_amdgcn_sched_barrier(0);
}

// Sentinel wait (r6-proven): every u32 word is either a written h-pair
// (halfwords < 0x8000 since h >= 0) or 0xFFFFFFFF poison. Re-issue until
// fresh. Rule #18: after VMWAIT, re-pin via volatile dep8 BEFORE the check.
template<int N, int M>
__device__ __forceinline__ void wait_fresh(short8 (&d)[M], const unsigned short* b, int koff) {
    int g = 0;
    for (;;) {
        VMWAIT(0);
        __builtin_amdgcn_sched_barrier(0);
        #pragma unroll
        for (int i = 0; i < N; ++i) dep8(d[i]);   // post-wait defs
        bool bad = false;
        #pragma unroll
        for (int i = 0; i < N; ++i) {
            union { short8 s; unsigned int w[4]; } u; u.s = d[i];
            #pragma unroll
            for (int j = 0; j < 4; ++j) bad |= (u.w[j] == 0xFFFFFFFFu);
        }
        if (__ballot(bad) == 0ull) break;
        if (++g > (1 << 15)) break;   // fail visibly, never hang
        #pragma unroll
        for (int i = 0; i < N; ++i) d[i] = llc_load(b + i * 16 + koff);
    }
}

// Persistent 2-layer LSTM, LAYER-SPLIT PIPELINE + DATA-SENTINEL sync.
// Blocks 0-127 = layer 1, 128-255 = layer 2, concurrent on separate CUs
// (139KB LDS -> 1 block/CU, all resident). Block = 32 rows x 32 units.
// NO FLAGS: h1h/h2h give every timestep a write-once buffer (poisoned 0xFF
// pre-launch). Producer sys-stores ARE the signal; consumers batch-load and
// re-issue until no poison word. Removes per step: flag publish+commit,
// poll->load serialization, store-drain (lds_barrier), and ALL L1<-L2
// backpressure (write-once => no WAR) -> pipelines fully decoupled.
__global__ __launch_bounds__(512, 1) void lstm_persist(
    const unsigned short* __restrict__ xb,
    const unsigned short* __restrict__ P1,
    const unsigned short* __restrict__ P2,
    const float* __restrict__ b1, const float* __restrict__ b2,
    unsigned short* __restrict__ h1h, unsigned short* __restrict__ h2h)
{
    const int bid  = blockIdx.x;
    const bool isL1 = (bid < 128);
    const int sub  = isL1 ? bid : (bid - 128);
    const int mo   = sub & 7;        // row-slab (32 rows)
    const int ug   = sub >> 3;       // 0..15: unit-group of 32 units
    const int tid  = threadIdx.x;
    const int w    = tid >> 6;       // wave 0..7
    const int lane = tid & 63;
    const int arow = lane & 31;
    const int koff = (lane >> 5) * 8;
    const int row  = mo * 32 + arow;

    __shared__ float red[8][4][32][33];   // 8 waves x 4 gate-tiles partials
    __shared__ float cst[32][32];         // cell state (rows x units)
    __shared__ float bias_s[4][32];

    for (int i = tid; i < 1024; i += 512) cst[i >> 5][i & 31] = 0.f;
    if (tid < 128) {
        const float* bb = isL1 ? b1 : b2;
        bias_s[tid >> 5][tid & 31] = bb[(tid >> 5) * U_ + ug * 32 + (tid & 31)];
    }

    if (isL1) {
        // ---------------- LAYER-1 pipeline ----------------
        // ktiles 0..35 (0-3 = x, 4-35 = h1). w0:0-4, w1:5-9, w2:10-14,
        // w3:15-19, w4:20-23, w5:24-27, w6:28-31, w7:32-35.
        const int kbase = (w < 4) ? w * 5 : 20 + (w - 4) * 4;
        const int kcnt  = (w < 4) ? 5 : 4;
        short8 wf[4][5];
        {
            const unsigned short* base = P1 + (size_t)ug * (4 * 36 * 512);
            #pragma unroll
            for (int q = 0; q < 4; ++q) {
                #pragma unroll
                for (int i = 0; i < 5; ++i) {
                    if (i < kcnt)
                        wf[q][i] = *(const short8*)(base
                            + ((size_t)(q * 36 + kbase + i) * 64 + lane) * 8);
                }
            }
        }
        __syncthreads();

        for (int k = 0; k < T_; ++k) {
            floatx16 acc[4];
            #pragma unroll
            for (int q = 0; q < 4; ++q) {
                #pragma unroll
                for (int i = 0; i < 16; ++i) acc[q][i] = 0.f;
            }

            if (w == 0) {   // x-part (no cross-block dep)
                const unsigned short* xbase = xb + ((size_t)row * T_ + k) * F_;
                #pragma unroll
                for (int g = 0; g < 4; ++g) {
                    short8 a = *(const short8*)(xbase + g * 16 + koff);
                    #pragma unroll
                    for (int q = 0; q < 4; ++q) acc[q] = MFMA32(a, wf[q][g], acc[q]);
                }
            }

            if (k >= 1) {   // h-part: load IS the poll (sentinel)
                if (w == 0) {
                    const unsigned short* hb = h1h + (size_t)(k - 1) * BU_
                                               + (size_t)row * U_;
                    short8 fa[1];
                    fa[0] = llc_load(hb + koff);
                    wait_fresh<1>(fa, hb, koff);
                    dep8(fa[0]);
                    #pragma unroll
                    for (int q = 0; q < 4; ++q) acc[q] = MFMA32(fa[0], wf[q][4], acc[q]);
                } else if (w < 4) {
                    const unsigned short* hb = h1h + (size_t)(k - 1) * BU_
                                               + (size_t)row * U_ + (kbase - 4) * 16;
                    short8 fa[5];
                    #pragma unroll
                    for (int i = 0; i < 5; ++i) fa[i] = llc_load(hb + i * 16 + koff);
                    wait_fresh<5>(fa, hb, koff);
                    #pragma unroll
                    for (int i = 0; i < 5; ++i) {
                        dep8(fa[i]);
                        #pragma unroll
                        for (int q = 0; q < 4; ++q) acc[q] = MFMA32(fa[i], wf[q][i], acc[q]);
                    }
                } else {
                    const unsigned short* hb = h1h + (size_t)(k - 1) * BU_
                                               + (size_t)row * U_ + (kbase - 4) * 16;
                    short8 fa[4];
                    #pragma unroll
                    for (int i = 0; i < 4; ++i) fa[i] = llc_load(hb + i * 16 + koff);
                    wait_fresh<4>(fa, hb, koff);
                    #pragma unroll
                    for (int i = 0; i < 4; ++i) {
                        dep8(fa[i]);
                        #pragma unroll
                        for (int q = 0; q < 4; ++q) acc[q] = MFMA32(fa[i], wf[q][i], acc[q]);
                    }
                }
            }

            // D layout: col=lane&31 (unit), row=(r&3)+8*(r>>2)+4*(lane>>5)
            #pragma unroll
            for (int r = 0; r < 16; ++r) {
                int rr = (r & 3) + 8 * (r >> 2) + 4 * (lane >> 5);
                #pragma unroll
                for (int q = 0; q < 4; ++q) red[w][q][rr][arow] = acc[q][r];
            }
            lds_barrier();

            {   // epilogue: 512 thr = 32 rows x 16 unit-pairs
                int r = tid >> 4, u2 = (tid & 15) * 2;
                unsigned int pk = 0;
                #pragma unroll
                for (int du = 0; du < 2; ++du) {
                    int u = u2 + du;
                    float zi = 0.f, zf = 0.f, zg = 0.f, zo = 0.f;
                    #pragma unroll
                    for (int ww = 0; ww < 8; ++ww) {
                        zi += red[ww][0][r][u];
                        zf += red[ww][1][r][u];
                        zg += red[ww][2][r][u];
                        zo += red[ww][3][r][u];
                    }
                    zi += bias_s[0][u]; zf += bias_s[1][u];
                    zg += bias_s[2][u]; zo += bias_s[3][u];
                    float si = 1.f / (1.f + __expf(-zi));
                    float sf = 1.f / (1.f + __expf(-zf));
                    float so = 1.f / (1.f + __expf(-zo));
                    float gg = zg > 0.f ? zg : 0.f;
                    float cn = sf * cst[r][u] + si * gg;
                    cst[r][u] = cn;
                    float hn = so * (cn > 0.f ? cn : 0.f);
                    pk |= ((unsigned int)f2bf(hn)) << (16 * du);
                }
                unsigned int* hp = (unsigned int*)(h1h + (size_t)k * BU_
                                   + (size_t)(mo * 32 + r) * U_ + ug * 32 + u2);
                sys_store_u32(hp, pk);   // the store IS the signal
            }
            lds_barrier();
        }
    } else {
        // ---------------- LAYER-2 pipeline ----------------
        // ktiles 0..63: 0-31 = W2 (h1[t] input), 32-63 = U2 (h2[t-1]).
        // wave w: ktiles w*8..w*8+7 (w<4: pure h1; w>=4: pure h2).
        short8 wf[4][8];
        {
            const unsigned short* base = P2 + (size_t)ug * (4 * 64 * 512);
            #pragma unroll
            for (int q = 0; q < 4; ++q) {
                #pragma unroll
                for (int i = 0; i < 8; ++i)
                    wf[q][i] = *(const short8*)(base
                        + ((size_t)(q * 64 + w * 8 + i) * 64 + lane) * 8);
            }
        }
        __syncthreads();

        for (int t = 0; t < T_; ++t) {
            floatx16 acc[4];
            #pragma unroll
            for (int q = 0; q < 4; ++q) {
                #pragma unroll
                for (int i = 0; i < 16; ++i) acc[q][i] = 0.f;
            }

            const bool isU2 = (w >= 4);
            if (!isU2 || t >= 1) {
                const unsigned short* hb = isU2
                    ? h2h + (size_t)(t - 1) * BU_ + (size_t)row * U_ + (w - 4) * 128
                    : h1h + (size_t)t * BU_       + (size_t)row * U_ + w * 128;
                short8 fb[8];
                #pragma unroll
                for (int i = 0; i < 8; ++i) fb[i] = llc_load(hb + i * 16 + koff);
                wait_fresh<8>(fb, hb, koff);
                #pragma unroll
                for (int i = 0; i < 8; ++i) {
                    dep8(fb[i]);
                    #pragma unroll
                    for (int q = 0; q < 4; ++q) acc[q] = MFMA32(fb[i], wf[q][i], acc[q]);
                }
            }

            #pragma unroll
            for (int r = 0; r < 16; ++r) {
                int rr = (r & 3) + 8 * (r >> 2) + 4 * (lane >> 5);
                #pragma unroll
                for (int q = 0; q < 4; ++q) red[w][q][rr][arow] = acc[q][r];
            }
            lds_barrier();

            {   // epilogue
                int r = tid >> 4, u2 = (tid & 15) * 2;
                unsigned int pk = 0;
                #pragma unroll
                for (int du = 0; du < 2; ++du) {
                    int u = u2 + du;
                    float zi = 0.f, zf = 0.f, zg = 0.f, zo = 0.f;
                    #pragma unroll
                    for (int ww = 0; ww < 8; ++ww) {
                        zi += red[ww][0][r][u];
                        zf += red[ww][1][r][u];
                        zg += red[ww][2][r][u];
                        zo += red[ww][3][r][u];
                    }
                    zi += bias_s[0][u]; zf += bias_s[1][u];
                    zg += bias_s[2][u]; zo += bias_s[3][u];
                    float si = 1.f / (1.f + __expf(-zi));
                    float sf = 1.f / (1.f + __expf(-zf));
                    float so = 1.f / (1.f + __expf(-zo));
                    float gg = zg > 0.f ? zg : 0.f;
                    float cn = sf * cst[r][u] + si * gg;
                    cst[r][u] = cn;
                    float hn = so * (cn > 0.f ? cn : 0.f);
                    pk |= ((unsigned int)f2bf(hn)) << (16 * du);
                }
                unsigned int* hp = (unsigned int*)(h2h + (size_t)t * BU_
                                   + (size_t)(mo * 32 + r) * U_ + ug * 32 + u2);
                sys_store_u32(hp, pk);
            }
            lds_barrier();
        }
    }
}

__global__ void dense_kernel(const unsigned short* __restrict__ h2,
                             const float* __restrict__ Wd,
                             const float* __restrict__ bd,
                             float* __restrict__ out) {
    int b = blockIdx.x;
    int lane = threadIdx.x;                  // 64 lanes
    const unsigned short* hp = h2 + (long)b * U_ + lane * 8;
    float sum = 0.f;
    #pragma unroll
    for (int j = 0; j < 8; ++j) sum += bf2f(hp[j]) * Wd[lane * 8 + j];
    #pragma unroll
    for (int off = 32; off; off >>= 1) sum += __shfl_down(sum, off);
    if (lane == 0) out[b] = 1.f / (1.f + __expf(-(sum + bd[0])));
}

extern "C" void kernel_launch(void* const* d_in, const int* in_sizes, int n_in,
                              void* d_out, int out_size, void* d_ws, size_t ws_size,
                              hipStream_t stream) {
    const float* x  = (const float*)d_in[0];
    const float* W1 = (const float*)d_in[1];
    const float* U1 = (const float*)d_in[2];
    const float* b1 = (const float*)d_in[3];
    const float* W2 = (const float*)d_in[4];
    const float* U2 = (const float*)d_in[5];
    const float* b2 = (const float*)d_in[6];
    const float* Wd = (const float*)d_in[7];
    const float* bd = (const float*)d_in[8];
    float* out = (float*)d_out;

    char* ws = (char*)d_ws;
    size_t off = 0;
    unsigned short* xb  = (unsigned short*)(ws + off); off += (size_t)B_ * T_ * F_ * 2;      // 8.39 MB
    unsigned short* P1  = (unsigned short*)(ws + off); off += (size_t)16 * 4 * 36 * 512 * 2; // 2.36 MB
    unsigned short* P2  = (unsigned short*)(ws + off); off += (size_t)16 * 4 * 64 * 512 * 2; // 4.19 MB
    unsigned short* h1h = (unsigned short*)(ws + off); off += (size_t)T_ * BU_ * 2;          // 67.1 MB
    unsigned short* h2h = (unsigned short*)(ws + off); off += (size_t)T_ * BU_ * 2;          // 67.1 MB

    // Poison both h histories (write-once buffers; 0xFFFFFFFF = not written).
    // Stream-ordered before lstm_persist -> visibility via kernel-boundary
    // coherence. ~25us at memset BW.
    (void)hipMemsetAsync(h1h, 0xFF, (size_t)2 * T_ * BU_ * 2, stream);

    int n = B_ * T_ * F_;
    cast_x_kernel<<<(n + 255) / 256, 256, 0, stream>>>(x, xb, n);
    {
        long tot1 = 16L * 4 * 36 * 512;
        pack32_kernel<<<(int)((tot1 + 255) / 256), 256, 0, stream>>>(W1, U1, P1, 36, 64);
        long tot2 = 16L * 4 * 64 * 512;
        pack32_kernel<<<(int)((tot2 + 255) / 256), 256, 0, stream>>>(W2, U2, P2, 64, 512);
    }

    // 256 blocks x 512 thr; 139KB LDS/block -> exactly 1 block/CU, all
    // resident. Blocks 0-127 = layer-1 pipeline, 128-255 = layer-2.
    lstm_persist<<<256, 512, 0, stream>>>(xb, P1, P2, b1, b2, h1h, h2h);

    dense_kernel<<<B_, 64, 0, stream>>>(h2h + (size_t)(T_ - 1) * BU_,
                                        Wd, bd, out);
}